// Round 2
// baseline (4208.039 us; speedup 1.0000x reference)
//
#include <hip/hip_runtime.h>
#include <hip/hip_bf16.h>
#include <math.h>

#define N_TX   100000
#define N_USER 50000
#define F_TX   128
#define F_USER 64
#define HID    64
#define NH     4
#define OUTC   32
#define NE     500000
#define HC1    256          // NH*HID
#define SLOPE  0.2f

__device__ __forceinline__ float elu_f(float x) { return x > 0.f ? x : (expf(x) - 1.f); }

// ---------------- tiled fp32 GEMM: C = act(A[N,K] @ B[K,M] + bias) ----------------
// act: 0 = none, 1 = elu. K must be a multiple of 16.
__global__ __launch_bounds__(256) void gemm_kernel(const float* __restrict__ A,
    const float* __restrict__ B, const float* __restrict__ bias,
    float* __restrict__ C, int N, int K, int M, int act)
{
    __shared__ float As[16][65];
    __shared__ float Bs[16][65];
    const int tid = threadIdx.x;
    const int tx = tid % 16, ty = tid / 16;
    const int row0 = blockIdx.y * 64, col0 = blockIdx.x * 64;
    float acc[4][4] = {};
    for (int k0 = 0; k0 < K; k0 += 16) {
        #pragma unroll
        for (int i = 0; i < 4; ++i) {
            int idx = tid * 4 + i;           // 64x16 A tile
            int r = idx >> 4, kk = idx & 15;
            int gr = row0 + r;
            As[kk][r] = (gr < N) ? A[(size_t)gr * K + (k0 + kk)] : 0.f;
        }
        #pragma unroll
        for (int i = 0; i < 4; ++i) {
            int idx = tid * 4 + i;           // 16x64 B tile
            int kk = idx >> 6, c = idx & 63;
            int gc = col0 + c;
            Bs[kk][c] = (gc < M) ? B[(size_t)(k0 + kk) * M + gc] : 0.f;
        }
        __syncthreads();
        #pragma unroll
        for (int kk = 0; kk < 16; ++kk) {
            float a4[4], b4[4];
            #pragma unroll
            for (int i = 0; i < 4; ++i) a4[i] = As[kk][ty * 4 + i];
            #pragma unroll
            for (int j = 0; j < 4; ++j) b4[j] = Bs[kk][tx * 4 + j];
            #pragma unroll
            for (int i = 0; i < 4; ++i)
                #pragma unroll
                for (int j = 0; j < 4; ++j) acc[i][j] += a4[i] * b4[j];
        }
        __syncthreads();
    }
    #pragma unroll
    for (int i = 0; i < 4; ++i) {
        int r = row0 + ty * 4 + i;
        if (r >= N) continue;
        #pragma unroll
        for (int j = 0; j < 4; ++j) {
            int c = col0 + tx * 4 + j;
            if (c >= M) continue;
            float v = acc[i][j] + (bias ? bias[c] : 0.f);
            if (act == 1) v = elu_f(v);
            C[(size_t)r * M + c] = v;
        }
    }
}

// ------------- fold attention vectors into weights: Mv[k,h] = sum_c W[k,h*C+c]*a[h,c] -------------
struct AVArgs  { const float* W; const float* a; float* out; int K; int H; int C; };
struct AVArgs6 { AVArgs t[6]; };

__global__ void attn_vecs_kernel(AVArgs6 args)
{
    AVArgs A = args.t[blockIdx.x];
    int tid = threadIdx.x;
    if (tid < A.K * A.H) {
        int k = tid % A.K, h = tid / A.K;
        float s = 0.f;
        const float* wrow = A.W + (size_t)k * (A.H * A.C) + h * A.C;
        const float* arow = A.a + h * A.C;
        for (int c = 0; c < A.C; ++c) s += wrow[c] * arow[c];
        A.out[k * A.H + h] = s;
    }
}

// ------------- per-node attention scalars, K=64, H=4: out[n,h] = X[n,:] . Mv[:,h] -------------
__global__ void node_attn4(const float* __restrict__ X, const float* __restrict__ Mv,
                           float* __restrict__ out, int N)
{
    int wave = blockIdx.x * (blockDim.x >> 6) + (threadIdx.x >> 6);
    int lane = threadIdx.x & 63;
    if (wave >= N) return;
    float x = X[(size_t)wave * 64 + lane];
    float p0 = x * Mv[lane * 4 + 0];
    float p1 = x * Mv[lane * 4 + 1];
    float p2 = x * Mv[lane * 4 + 2];
    float p3 = x * Mv[lane * 4 + 3];
    for (int off = 32; off > 0; off >>= 1) {
        p0 += __shfl_down(p0, off);
        p1 += __shfl_down(p1, off);
        p2 += __shfl_down(p2, off);
        p3 += __shfl_down(p3, off);
    }
    if (lane == 0) {
        float* o = out + (size_t)wave * 4;
        o[0] = p0; o[1] = p1; o[2] = p2; o[3] = p3;
    }
}

// ------------- edge pass 1: w[e,h] = exp(leaky(als[src]+ald[dst])); den[dst,h] += w -------------
__global__ __launch_bounds__(256) void edge_w_kernel(const int* __restrict__ src,
    const int* __restrict__ dst, const float* __restrict__ als, const float* __restrict__ ald,
    float* __restrict__ w, float* __restrict__ den, int E, int H)
{
    int tid = blockIdx.x * blockDim.x + threadIdx.x;
    if (tid >= E * H) return;
    int e = tid / H, h = tid - e * H;
    int s = src[e], d = dst[e];
    float x = als[(size_t)s * H + h] + ald[(size_t)d * H + h];
    x = x > 0.f ? x : SLOPE * x;
    float ex = expf(x);
    w[tid] = ex;
    atomicAdd(den + (size_t)d * H + h, ex);
}

// ------------- conv1 edge aggregation (pre-transform): agg[d, h*64+c] += alpha_h * hsrc[s, c] ----
// 64 lanes per edge: lane = h*16 + sub, sub covers 16 float4s of the 64-float source row.
__global__ __launch_bounds__(256) void edge_agg4(const int* __restrict__ src,
    const int* __restrict__ dst, const float* __restrict__ w, const float* __restrict__ den,
    const float* __restrict__ hsrc, float* __restrict__ agg, int E)
{
    int eid = blockIdx.x * 4 + (threadIdx.x >> 6);
    int lane = threadIdx.x & 63;
    if (eid >= E) return;
    int s = src[eid], d = dst[eid];
    int h = lane >> 4, sub = lane & 15;
    float alpha = w[(size_t)eid * 4 + h] / (den[(size_t)d * 4 + h] + 1e-16f);
    float4 v = ((const float4*)(hsrc + (size_t)s * 64))[sub];
    float* o = agg + (size_t)d * 256 + h * 64 + sub * 4;
    atomicAdd(o + 0, v.x * alpha);
    atomicAdd(o + 1, v.y * alpha);
    atomicAdd(o + 2, v.z * alpha);
    atomicAdd(o + 3, v.w * alpha);
}

// ------------- conv2 edge aggregation: agg[d, :32] += alpha * hs[s, :32], 8 lanes/edge ----------
__global__ __launch_bounds__(256) void edge_agg_c2(const int* __restrict__ src,
    const int* __restrict__ dst, const float* __restrict__ w, const float* __restrict__ den,
    const float* __restrict__ hs, float* __restrict__ agg, int E)
{
    int eid = blockIdx.x * 32 + (threadIdx.x >> 3);
    int lane = threadIdx.x & 7;
    if (eid >= E) return;
    int s = src[eid], d = dst[eid];
    float alpha = w[eid] / (den[d] + 1e-16f);
    float4 v = ((const float4*)(hs + (size_t)s * 32))[lane];
    float* o = agg + (size_t)d * 32 + lane * 4;
    atomicAdd(o + 0, v.x * alpha);
    atomicAdd(o + 1, v.y * alpha);
    atomicAdd(o + 2, v.z * alpha);
    atomicAdd(o + 3, v.w * alpha);
}

// ------------- post-aggregation per-head transform (dst side of conv1) -------------
// For node n, head h=blockIdx.y:  val[j] = elu( sum_c X[n,h*64+c] * W[c,h*64+j] + b[h*64+j] )
// if writeRows: X[n,h*64+j] = val[j] (in place).  Always: atomicAdd(dot_out[n], sum_j val[j]*vvec[h*64+j]).
// Thread-per-node; W/b/vvec rows are wave-uniform -> scalar loads + v_fmac with SGPR operand.
__global__ __launch_bounds__(256) void transform_head_kernel(
    float* __restrict__ X, const float* __restrict__ W, const float* __restrict__ b,
    const float* __restrict__ vvec, float* __restrict__ dot_out, int N, int writeRows)
{
    const int h = blockIdx.y;
    const int n = blockIdx.x * 256 + threadIdx.x;
    const bool act = (n < N);
    float acc[64];
    const float* brow = b + h * 64;
    #pragma unroll
    for (int j = 0; j < 64; ++j) acc[j] = brow[j];
    float* xrow = X + (size_t)n * 256 + h * 64;
    #pragma unroll 1
    for (int c0 = 0; c0 < 64; c0 += 4) {
        float4 x4 = make_float4(0.f, 0.f, 0.f, 0.f);
        if (act) x4 = *(const float4*)(xrow + c0);
        const float* wbase = W + (size_t)c0 * 256 + h * 64;
        #pragma unroll
        for (int cc = 0; cc < 4; ++cc) {
            const float xc = (cc == 0) ? x4.x : (cc == 1) ? x4.y : (cc == 2) ? x4.z : x4.w;
            const float* wrow = wbase + (size_t)cc * 256;
            #pragma unroll
            for (int j = 0; j < 64; ++j) acc[j] = fmaf(xc, wrow[j], acc[j]);
        }
    }
    float dsum = 0.f;
    const float* vrow = vvec + h * 64;
    #pragma unroll
    for (int j = 0; j < 64; ++j) {
        float v = acc[j];
        v = v > 0.f ? v : (expf(v) - 1.f);
        acc[j] = v;
        dsum += v * vrow[j];
    }
    if (!act) return;
    if (writeRows) {
        #pragma unroll
        for (int j = 0; j < 64; j += 4) {
            float4 o;
            o.x = acc[j]; o.y = acc[j + 1]; o.z = acc[j + 2]; o.w = acc[j + 3];
            *(float4*)(xrow + j) = o;
        }
    }
    atomicAdd(dot_out + n, dsum);
}

// ------------- fused t2 = elu(agg2 + b2); out = t2 @ Wc + bc -------------
__global__ void final_kernel(const float* __restrict__ agg2, const float* __restrict__ b2,
    const float* __restrict__ Wc, const float* __restrict__ bc,
    float* __restrict__ out, int N)
{
    int n = blockIdx.x * blockDim.x + threadIdx.x;
    if (n >= N) return;
    const float* r = agg2 + (size_t)n * OUTC;
    float acc = 0.f;
    #pragma unroll
    for (int c = 0; c < OUTC; ++c) acc += elu_f(r[c] + b2[c]) * Wc[c];
    out[n] = acc + bc[0];
}

extern "C" void kernel_launch(void* const* d_in, const int* in_sizes, int n_in,
                              void* d_out, int out_size, void* d_ws, size_t ws_size,
                              hipStream_t stream)
{
    const float* x_tx    = (const float*)d_in[0];
    const float* x_user  = (const float*)d_in[1];
    const int*   ei_u2t  = (const int*)d_in[2];
    const int*   ei_t2u  = (const int*)d_in[3];
    const float* Wp_tx   = (const float*)d_in[4];
    const float* bp_tx   = (const float*)d_in[5];
    const float* Wp_user = (const float*)d_in[6];
    const float* bp_user = (const float*)d_in[7];
    const float* W1_u2t  = (const float*)d_in[8];
    const float* as1_u2t = (const float*)d_in[9];
    const float* ad1_u2t = (const float*)d_in[10];
    const float* b1_u2t  = (const float*)d_in[11];
    const float* W2_u2t  = (const float*)d_in[12];
    const float* as2_u2t = (const float*)d_in[13];
    const float* ad2_u2t = (const float*)d_in[14];
    const float* b2_u2t  = (const float*)d_in[15];
    const float* W1_t2u  = (const float*)d_in[16];
    const float* as1_t2u = (const float*)d_in[17];
    const float* ad1_t2u = (const float*)d_in[18];
    const float* b1_t2u  = (const float*)d_in[19];
    const float* Wc      = (const float*)d_in[24];
    const float* bc      = (const float*)d_in[25];
    float* out = (float*)d_out;
    float* ws  = (float*)d_ws;

    const int* src_u2t = ei_u2t;            // user ids
    const int* dst_u2t = ei_u2t + NE;       // tx ids
    const int* src_t2u = ei_t2u;            // tx ids
    const int* dst_t2u = ei_t2u + NE;       // user ids

    // ---- workspace layout (floats); total 38,551,536 floats = 154.2 MB ----
    float* h_tx  = ws;                      //  6,400,000  (conv2 scratch aliases here later)
    float* h_us  = ws + 6400000;            //  3,200,000
    float* den   = ws + 9600000;            //    400,000  (shared u2t then t2u)
    float* agg   = ws + 10000000;           // 25,600,000  (shared; u1 ends up here in place)
    float* als2  = ws + 35600000;           //     50,000
    float* ald2  = ws + 35650000;           //    100,000
    float* als_s = ws + 35750000;           //    400,000  (sized for N_TX)
    float* ald_d = ws + 36150000;           //    400,000
    float* w_e   = ws + 36550000;           //  2,000,000  (shared)
    float* avec  = ws + 38550000;           //      1,536
    // conv2 scratch aliases dead h_tx region (5.4M <= 6.4M):
    float* hs2  = ws;                       //  1,600,000
    float* den2 = ws + 1600000;             //    100,000
    float* agg2 = ws + 1700000;             //  3,200,000  (den2+agg2 contiguous -> one memset)
    float* w2   = ws + 4900000;             //    500,000

    float* Msrc_u2t = avec + 0;
    float* Mdst_u2t = avec + 256;
    float* Msrc_t2u = avec + 512;
    float* Mdst_t2u = avec + 768;
    float* vsrc2    = avec + 1024;
    float* vdst2    = avec + 1280;

    // ---- fold attention vectors into weights ----
    AVArgs6 av;
    av.t[0] = { W1_u2t, as1_u2t, Msrc_u2t, HID, NH, HID };
    av.t[1] = { W1_u2t, ad1_u2t, Mdst_u2t, HID, NH, HID };
    av.t[2] = { W1_t2u, as1_t2u, Msrc_t2u, HID, NH, HID };
    av.t[3] = { W1_t2u, ad1_t2u, Mdst_t2u, HID, NH, HID };
    av.t[4] = { W2_u2t, as2_u2t, vsrc2, HC1, 1, OUTC };
    av.t[5] = { W2_u2t, ad2_u2t, vdst2, HC1, 1, OUTC };
    attn_vecs_kernel<<<6, 256, 0, stream>>>(av);

    // ---- zero den+agg+als2+ald2 (contiguous 26,150,000 floats) ----
    hipMemsetAsync(den, 0, 26150000 * sizeof(float), stream);

    // ---- input projections ----
    gemm_kernel<<<dim3(1, (N_TX + 63) / 64), 256, 0, stream>>>(
        x_tx, Wp_tx, bp_tx, h_tx, N_TX, F_TX, HID, 1);
    gemm_kernel<<<dim3(1, (N_USER + 63) / 64), 256, 0, stream>>>(
        x_user, Wp_user, bp_user, h_us, N_USER, F_USER, HID, 1);

    // ================= conv1, u2t (dst = tx) =================
    node_attn4<<<(N_USER + 3) / 4, 256, 0, stream>>>(h_us, Msrc_u2t, als_s, N_USER);
    node_attn4<<<(N_TX   + 3) / 4, 256, 0, stream>>>(h_tx, Mdst_u2t, ald_d, N_TX);
    edge_w_kernel<<<(NE * NH + 255) / 256, 256, 0, stream>>>(
        src_u2t, dst_u2t, als_s, ald_d, w_e, den, NE, NH);
    edge_agg4<<<(NE + 3) / 4, 256, 0, stream>>>(src_u2t, dst_u2t, w_e, den, h_us, agg, NE);
    // t1 never materialized: transform+bias+elu fused into ald2 = t1 . vdst2
    transform_head_kernel<<<dim3((N_TX + 255) / 256, NH), 256, 0, stream>>>(
        agg, W1_u2t, b1_u2t, vdst2, ald2, N_TX, 0);

    // ---- re-zero den+agg for t2u ----
    hipMemsetAsync(den, 0, 26000000 * sizeof(float), stream);

    // ================= conv1, t2u (dst = user) =================
    node_attn4<<<(N_TX   + 3) / 4, 256, 0, stream>>>(h_tx, Msrc_t2u, als_s, N_TX);
    node_attn4<<<(N_USER + 3) / 4, 256, 0, stream>>>(h_us, Mdst_t2u, ald_d, N_USER);
    edge_w_kernel<<<(NE * NH + 255) / 256, 256, 0, stream>>>(
        src_t2u, dst_t2u, als_s, ald_d, w_e, den, NE, NH);
    edge_agg4<<<(NE + 3) / 4, 256, 0, stream>>>(src_t2u, dst_t2u, w_e, den, h_tx, agg, NE);
    // u1 = elu(agg @ blockdiag(W1_t2u) + b1) written in place; als2 = u1 . vsrc2 fused
    transform_head_kernel<<<dim3((N_USER + 255) / 256, NH), 256, 0, stream>>>(
        agg, W1_t2u, b1_t2u, vsrc2, als2, N_USER, 1);
    float* u1 = agg;

    // ================= conv2, u2t only (h_tx/h_us now dead; scratch aliases them) ======
    hipMemsetAsync(den2, 0, 3300000 * sizeof(float), stream);   // den2 + agg2
    gemm_kernel<<<dim3(1, (N_USER + 63) / 64), 256, 0, stream>>>(
        u1, W2_u2t, nullptr, hs2, N_USER, HC1, OUTC, 0);
    edge_w_kernel<<<(NE + 255) / 256, 256, 0, stream>>>(
        src_u2t, dst_u2t, als2, ald2, w2, den2, NE, 1);
    edge_agg_c2<<<(NE + 31) / 32, 256, 0, stream>>>(
        src_u2t, dst_u2t, w2, den2, hs2, agg2, NE);

    // ---- classifier ----
    final_kernel<<<(N_TX + 255) / 256, 256, 0, stream>>>(agg2, b2_u2t, Wc, bc, out, N_TX);
}

// Round 3
// 841.716 us; speedup vs baseline: 4.9994x; 4.9994x over previous
//
#include <hip/hip_runtime.h>
#include <hip/hip_bf16.h>
#include <math.h>

#define N_TX   100000
#define N_USER 50000
#define F_TX   128
#define F_USER 64
#define HID    64
#define NH     4
#define OUTC   32
#define NE     500000
#define HC1    256          // NH*HID
#define SLOPE  0.2f

__device__ __forceinline__ float elu_f(float x) { return x > 0.f ? x : (expf(x) - 1.f); }
__device__ __forceinline__ float lrelu_exp(float x) { x = x > 0.f ? x : SLOPE * x; return expf(x); }

// ---------------- tiled fp32 GEMM: C = act(A[N,K] @ B[K,M] + bias) ----------------
__global__ __launch_bounds__(256) void gemm_kernel(const float* __restrict__ A,
    const float* __restrict__ B, const float* __restrict__ bias,
    float* __restrict__ C, int N, int K, int M, int act)
{
    __shared__ float As[16][65];
    __shared__ float Bs[16][65];
    const int tid = threadIdx.x;
    const int tx = tid % 16, ty = tid / 16;
    const int row0 = blockIdx.y * 64, col0 = blockIdx.x * 64;
    float acc[4][4] = {};
    for (int k0 = 0; k0 < K; k0 += 16) {
        #pragma unroll
        for (int i = 0; i < 4; ++i) {
            int idx = tid * 4 + i;           // 64x16 A tile
            int r = idx >> 4, kk = idx & 15;
            int gr = row0 + r;
            As[kk][r] = (gr < N) ? A[(size_t)gr * K + (k0 + kk)] : 0.f;
        }
        #pragma unroll
        for (int i = 0; i < 4; ++i) {
            int idx = tid * 4 + i;           // 16x64 B tile
            int kk = idx >> 6, c = idx & 63;
            int gc = col0 + c;
            Bs[kk][c] = (gc < M) ? B[(size_t)(k0 + kk) * M + gc] : 0.f;
        }
        __syncthreads();
        #pragma unroll
        for (int kk = 0; kk < 16; ++kk) {
            float a4[4], b4[4];
            #pragma unroll
            for (int i = 0; i < 4; ++i) a4[i] = As[kk][ty * 4 + i];
            #pragma unroll
            for (int j = 0; j < 4; ++j) b4[j] = Bs[kk][tx * 4 + j];
            #pragma unroll
            for (int i = 0; i < 4; ++i)
                #pragma unroll
                for (int j = 0; j < 4; ++j) acc[i][j] += a4[i] * b4[j];
        }
        __syncthreads();
    }
    #pragma unroll
    for (int i = 0; i < 4; ++i) {
        int r = row0 + ty * 4 + i;
        if (r >= N) continue;
        #pragma unroll
        for (int j = 0; j < 4; ++j) {
            int c = col0 + tx * 4 + j;
            if (c >= M) continue;
            float v = acc[i][j] + (bias ? bias[c] : 0.f);
            if (act == 1) v = elu_f(v);
            C[(size_t)r * M + c] = v;
        }
    }
}

// ------------- fold attention vectors into weights: Mv[k,h] = sum_c W[k,h*C+c]*a[h,c] -------------
struct AVArgs  { const float* W; const float* a; float* out; int K; int H; int C; };
struct AVArgs6 { AVArgs t[6]; };

__global__ void attn_vecs_kernel(AVArgs6 args)
{
    AVArgs A = args.t[blockIdx.x];
    int tid = threadIdx.x;
    if (tid < A.K * A.H) {
        int k = tid % A.K, h = tid / A.K;
        float s = 0.f;
        const float* wrow = A.W + (size_t)k * (A.H * A.C) + h * A.C;
        const float* arow = A.a + h * A.C;
        for (int c = 0; c < A.C; ++c) s += wrow[c] * arow[c];
        A.out[k * A.H + h] = s;
    }
}

// ------------- per-node attention scalars, K=64, H=4 -------------
__global__ void node_attn4(const float* __restrict__ X, const float* __restrict__ Mv,
                           float* __restrict__ out, int N)
{
    int wave = blockIdx.x * (blockDim.x >> 6) + (threadIdx.x >> 6);
    int lane = threadIdx.x & 63;
    if (wave >= N) return;
    float x = X[(size_t)wave * 64 + lane];
    float p0 = x * Mv[lane * 4 + 0];
    float p1 = x * Mv[lane * 4 + 1];
    float p2 = x * Mv[lane * 4 + 2];
    float p3 = x * Mv[lane * 4 + 3];
    for (int off = 32; off > 0; off >>= 1) {
        p0 += __shfl_down(p0, off);
        p1 += __shfl_down(p1, off);
        p2 += __shfl_down(p2, off);
        p3 += __shfl_down(p3, off);
    }
    if (lane == 0) {
        float* o = out + (size_t)wave * 4;
        o[0] = p0; o[1] = p1; o[2] = p2; o[3] = p3;
    }
}

// ================= CSR build =================
__global__ __launch_bounds__(256) void hist_kernel(const int* __restrict__ dst,
    int* __restrict__ deg, int E)
{
    int e = blockIdx.x * 256 + threadIdx.x;
    if (e < E) atomicAdd(&deg[dst[e]], 1);
}

__global__ __launch_bounds__(256) void block_sum_kernel(const int* __restrict__ deg,
    int* __restrict__ bsum, int Nd)
{
    __shared__ int lds[256];
    int t = threadIdx.x;
    int i = blockIdx.x * 256 + t;
    lds[t] = (i < Nd) ? deg[i] : 0;
    __syncthreads();
    for (int o = 128; o > 0; o >>= 1) {
        if (t < o) lds[t] += lds[t + o];
        __syncthreads();
    }
    if (t == 0) bsum[blockIdx.x] = lds[0];
}

// in-place exclusive scan of bsum[0..nb), nb <= 512, single block of 512
__global__ __launch_bounds__(512) void scan_bsum_kernel(int* __restrict__ bsum, int nb)
{
    __shared__ int lds[512];
    int t = threadIdx.x;
    int v = (t < nb) ? bsum[t] : 0;
    lds[t] = v;
    __syncthreads();
    for (int o = 1; o < 512; o <<= 1) {
        int x = (t >= o) ? lds[t - o] : 0;
        __syncthreads();
        lds[t] += x;
        __syncthreads();
    }
    if (t < nb) bsum[t] = lds[t] - v;   // exclusive
}

__global__ __launch_bounds__(256) void scan_final_kernel(const int* __restrict__ deg,
    const int* __restrict__ bsum_excl, int* __restrict__ rowptr, int* __restrict__ cursor,
    int Nd, int E)
{
    __shared__ int lds[256];
    int t = threadIdx.x;
    int i = blockIdx.x * 256 + t;
    int v = (i < Nd) ? deg[i] : 0;
    lds[t] = v;
    __syncthreads();
    for (int o = 1; o < 256; o <<= 1) {
        int x = (t >= o) ? lds[t - o] : 0;
        __syncthreads();
        lds[t] += x;
        __syncthreads();
    }
    int excl = lds[t] - v + bsum_excl[blockIdx.x];
    if (i < Nd) {
        rowptr[i] = excl;
        cursor[i] = excl;
        if (i == Nd - 1) rowptr[Nd] = E;
    }
}

__global__ __launch_bounds__(256) void scatter_kernel(const int* __restrict__ src,
    const int* __restrict__ dst, int* __restrict__ cursor, int* __restrict__ csr, int E)
{
    int e = blockIdx.x * 256 + threadIdx.x;
    if (e < E) {
        int p = atomicAdd(&cursor[dst[e]], 1);
        csr[p] = src[e];
    }
}

// ================= conv1 aggregation: one wave per dst node =================
// agg[d, h*64+lane] = sum_e w_h(e) * hsrc[s_e, lane] / (sum_e w_h(e) + eps)
__global__ __launch_bounds__(256) void agg_conv1_kernel(const int* __restrict__ rowptr,
    const int* __restrict__ csr, const float* __restrict__ hsrc,
    const float* __restrict__ als, const float* __restrict__ ald,
    float* __restrict__ agg, int Nd)
{
    int d = blockIdx.x * 4 + (threadIdx.x >> 6);
    int lane = threadIdx.x & 63;
    if (d >= Nd) return;
    int beg = rowptr[d], end = rowptr[d + 1];
    float4 A = *(const float4*)(ald + (size_t)d * 4);
    float a0 = 0.f, a1 = 0.f, a2 = 0.f, a3 = 0.f;
    float w0 = 0.f, w1 = 0.f, w2 = 0.f, w3 = 0.f;
    #pragma unroll 2
    for (int i = beg; i < end; ++i) {
        int s = csr[i];
        float4 v = *(const float4*)(als + (size_t)s * 4);
        float e0 = lrelu_exp(v.x + A.x);
        float e1 = lrelu_exp(v.y + A.y);
        float e2 = lrelu_exp(v.z + A.z);
        float e3 = lrelu_exp(v.w + A.w);
        float x = hsrc[(size_t)s * 64 + lane];
        a0 = fmaf(e0, x, a0); w0 += e0;
        a1 = fmaf(e1, x, a1); w1 += e1;
        a2 = fmaf(e2, x, a2); w2 += e2;
        a3 = fmaf(e3, x, a3); w3 += e3;
    }
    float* o = agg + (size_t)d * 256;
    o[lane]       = a0 / (w0 + 1e-16f);
    o[64 + lane]  = a1 / (w1 + 1e-16f);
    o[128 + lane] = a2 / (w2 + 1e-16f);
    o[192 + lane] = a3 / (w3 + 1e-16f);
}

// ------------- post-aggregation per-head transform (dst side of conv1) -------------
__global__ __launch_bounds__(256) void transform_head_kernel(
    float* __restrict__ X, const float* __restrict__ W, const float* __restrict__ b,
    const float* __restrict__ vvec, float* __restrict__ dot_out, int N, int writeRows)
{
    const int h = blockIdx.y;
    const int n = blockIdx.x * 256 + threadIdx.x;
    const bool act = (n < N);
    float acc[64];
    const float* brow = b + h * 64;
    #pragma unroll
    for (int j = 0; j < 64; ++j) acc[j] = brow[j];
    float* xrow = X + (size_t)n * 256 + h * 64;
    #pragma unroll 1
    for (int c0 = 0; c0 < 64; c0 += 4) {
        float4 x4 = make_float4(0.f, 0.f, 0.f, 0.f);
        if (act) x4 = *(const float4*)(xrow + c0);
        const float* wbase = W + (size_t)c0 * 256 + h * 64;
        #pragma unroll
        for (int cc = 0; cc < 4; ++cc) {
            const float xc = (cc == 0) ? x4.x : (cc == 1) ? x4.y : (cc == 2) ? x4.z : x4.w;
            const float* wrow = wbase + (size_t)cc * 256;
            #pragma unroll
            for (int j = 0; j < 64; ++j) acc[j] = fmaf(xc, wrow[j], acc[j]);
        }
    }
    float dsum = 0.f;
    const float* vrow = vvec + h * 64;
    #pragma unroll
    for (int j = 0; j < 64; ++j) {
        float v = acc[j];
        v = v > 0.f ? v : (expf(v) - 1.f);
        acc[j] = v;
        dsum += v * vrow[j];
    }
    if (!act) return;
    if (writeRows) {
        #pragma unroll
        for (int j = 0; j < 64; j += 4) {
            float4 o;
            o.x = acc[j]; o.y = acc[j + 1]; o.z = acc[j + 2]; o.w = acc[j + 3];
            *(float4*)(xrow + j) = o;
        }
    }
    atomicAdd(dot_out + n, dsum);
}

// ================= conv2: fused edge-softmax + aggregation + bias/ELU + classifier ==========
// one wave per dst (tx) node; two edges in flight (lane halves); 32 channels
__global__ __launch_bounds__(256) void conv2_fused_kernel(const int* __restrict__ rowptr,
    const int* __restrict__ csr, const float* __restrict__ hs2,
    const float* __restrict__ als2, const float* __restrict__ ald2,
    const float* __restrict__ b2, const float* __restrict__ Wc, const float* __restrict__ bc,
    float* __restrict__ out, int Nd)
{
    int d = blockIdx.x * 4 + (threadIdx.x >> 6);
    int lane = threadIdx.x & 63;
    if (d >= Nd) return;
    int beg = rowptr[d], end = rowptr[d + 1];
    float aldd = ald2[d];
    int half = lane >> 5, c = lane & 31;
    float acc = 0.f, wsum = 0.f;
    for (int i = beg + half; i < end; i += 2) {
        int s = csr[i];
        float w = lrelu_exp(als2[s] + aldd);
        acc = fmaf(w, hs2[(size_t)s * 32 + c], acc);
        wsum += w;
    }
    acc  += __shfl_down(acc, 32);
    wsum += __shfl_down(wsum, 32);
    float val = 0.f;
    if (lane < 32) {
        float t2 = acc / (wsum + 1e-16f) + b2[c];
        t2 = t2 > 0.f ? t2 : (expf(t2) - 1.f);
        val = t2 * Wc[c];
    }
    #pragma unroll
    for (int o = 16; o > 0; o >>= 1) val += __shfl_down(val, o);
    if (lane == 0) out[d] = val + bc[0];
}

extern "C" void kernel_launch(void* const* d_in, const int* in_sizes, int n_in,
                              void* d_out, int out_size, void* d_ws, size_t ws_size,
                              hipStream_t stream)
{
    const float* x_tx    = (const float*)d_in[0];
    const float* x_user  = (const float*)d_in[1];
    const int*   ei_u2t  = (const int*)d_in[2];
    const int*   ei_t2u  = (const int*)d_in[3];
    const float* Wp_tx   = (const float*)d_in[4];
    const float* bp_tx   = (const float*)d_in[5];
    const float* Wp_user = (const float*)d_in[6];
    const float* bp_user = (const float*)d_in[7];
    const float* W1_u2t  = (const float*)d_in[8];
    const float* as1_u2t = (const float*)d_in[9];
    const float* ad1_u2t = (const float*)d_in[10];
    const float* b1_u2t  = (const float*)d_in[11];
    const float* W2_u2t  = (const float*)d_in[12];
    const float* as2_u2t = (const float*)d_in[13];
    const float* ad2_u2t = (const float*)d_in[14];
    const float* b2_u2t  = (const float*)d_in[15];
    const float* W1_t2u  = (const float*)d_in[16];
    const float* as1_t2u = (const float*)d_in[17];
    const float* ad1_t2u = (const float*)d_in[18];
    const float* b1_t2u  = (const float*)d_in[19];
    const float* Wc      = (const float*)d_in[24];
    const float* bc      = (const float*)d_in[25];
    float* out = (float*)d_out;
    float* ws  = (float*)d_ws;

    const int* src_u2t = ei_u2t;            // user ids
    const int* dst_u2t = ei_u2t + NE;       // tx ids
    const int* src_t2u = ei_t2u;            // tx ids
    const int* dst_u   = ei_t2u + NE;       // user ids

    // ---- workspace layout (floats) ----
    float* h_tx  = ws;                      //  6,400,000  (conv2 hs2 aliases later)
    float* h_us  = ws + 6400000;            //  3,200,000
    float* agg   = ws + 9600000;            // 25,600,000  (u1 ends here in place)
    float* als2  = ws + 35200000;           //     50,000
    float* ald2  = ws + 35250000;           //    100,000  (als2+ald2 contiguous -> one memset)
    float* als_s = ws + 35350000;           //    400,000  (sized for N_TX)
    float* ald_d = ws + 35750000;           //    400,000
    float* avec  = ws + 36150000;           //      1,536
    // ---- int region ----
    int* ibase    = (int*)(ws + 36152000);
    int* deg_t    = ibase;                  //   100,000  (deg_t+deg_u contiguous -> one memset)
    int* deg_u    = ibase + 100000;         //    50,000
    int* rowptr_t = ibase + 150000;         //   100,001
    int* cur_t    = ibase + 250001;         //   100,000
    int* csr_t    = ibase + 350001;         //   500,000
    int* rowptr_u = ibase + 850001;         //    50,001
    int* cur_u    = ibase + 900002;         //    50,000
    int* csr_u    = ibase + 950002;         //   500,000
    int* bsum_t   = ibase + 1450002;        //       512
    int* bsum_u   = ibase + 1450514;        //       512
    // ends at float offset 36,152,000 + 1,451,026 = 37,603,026 floats = 150.4 MB

    // conv2 scratch aliases dead h_tx region (1.6M <= 6.4M):
    float* hs2 = ws;

    float* Msrc_u2t = avec + 0;
    float* Mdst_u2t = avec + 256;
    float* Msrc_t2u = avec + 512;
    float* Mdst_t2u = avec + 768;
    float* vsrc2    = avec + 1024;
    float* vdst2    = avec + 1280;

    const int NB_T = (N_TX + 255) / 256;    // 391
    const int NB_U = (N_USER + 255) / 256;  // 196

    // ---- fold attention vectors into weights ----
    AVArgs6 av;
    av.t[0] = { W1_u2t, as1_u2t, Msrc_u2t, HID, NH, HID };
    av.t[1] = { W1_u2t, ad1_u2t, Mdst_u2t, HID, NH, HID };
    av.t[2] = { W1_t2u, as1_t2u, Msrc_t2u, HID, NH, HID };
    av.t[3] = { W1_t2u, ad1_t2u, Mdst_t2u, HID, NH, HID };
    av.t[4] = { W2_u2t, as2_u2t, vsrc2, HC1, 1, OUTC };
    av.t[5] = { W2_u2t, ad2_u2t, vdst2, HC1, 1, OUTC };
    attn_vecs_kernel<<<6, 256, 0, stream>>>(av);

    // ---- zero: als2+ald2 (atomic dests), deg_t+deg_u ----
    hipMemsetAsync(als2, 0, 150000 * sizeof(float), stream);
    hipMemsetAsync(deg_t, 0, 150000 * sizeof(int), stream);

    // ---- CSR build for u2t (dst = tx) ----
    hist_kernel<<<(NE + 255) / 256, 256, 0, stream>>>(dst_u2t, deg_t, NE);
    block_sum_kernel<<<NB_T, 256, 0, stream>>>(deg_t, bsum_t, N_TX);
    scan_bsum_kernel<<<1, 512, 0, stream>>>(bsum_t, NB_T);
    scan_final_kernel<<<NB_T, 256, 0, stream>>>(deg_t, bsum_t, rowptr_t, cur_t, N_TX, NE);
    scatter_kernel<<<(NE + 255) / 256, 256, 0, stream>>>(src_u2t, dst_u2t, cur_t, csr_t, NE);

    // ---- CSR build for t2u (dst = user) ----
    hist_kernel<<<(NE + 255) / 256, 256, 0, stream>>>(dst_u, deg_u, NE);
    block_sum_kernel<<<NB_U, 256, 0, stream>>>(deg_u, bsum_u, N_USER);
    scan_bsum_kernel<<<1, 512, 0, stream>>>(bsum_u, NB_U);
    scan_final_kernel<<<NB_U, 256, 0, stream>>>(deg_u, bsum_u, rowptr_u, cur_u, N_USER, NE);
    scatter_kernel<<<(NE + 255) / 256, 256, 0, stream>>>(src_t2u, dst_u, cur_u, csr_u, NE);

    // ---- input projections ----
    gemm_kernel<<<dim3(1, (N_TX + 63) / 64), 256, 0, stream>>>(
        x_tx, Wp_tx, bp_tx, h_tx, N_TX, F_TX, HID, 1);
    gemm_kernel<<<dim3(1, (N_USER + 63) / 64), 256, 0, stream>>>(
        x_user, Wp_user, bp_user, h_us, N_USER, F_USER, HID, 1);

    // ================= conv1, u2t (dst = tx) =================
    node_attn4<<<(N_USER + 3) / 4, 256, 0, stream>>>(h_us, Msrc_u2t, als_s, N_USER);
    node_attn4<<<(N_TX   + 3) / 4, 256, 0, stream>>>(h_tx, Mdst_u2t, ald_d, N_TX);
    agg_conv1_kernel<<<(N_TX + 3) / 4, 256, 0, stream>>>(
        rowptr_t, csr_t, h_us, als_s, ald_d, agg, N_TX);
    // t1 never materialized: transform+bias+elu fused into ald2 = t1 . vdst2
    transform_head_kernel<<<dim3((N_TX + 255) / 256, NH), 256, 0, stream>>>(
        agg, W1_u2t, b1_u2t, vdst2, ald2, N_TX, 0);

    // ================= conv1, t2u (dst = user) =================
    node_attn4<<<(N_TX   + 3) / 4, 256, 0, stream>>>(h_tx, Msrc_t2u, als_s, N_TX);
    node_attn4<<<(N_USER + 3) / 4, 256, 0, stream>>>(h_us, Mdst_t2u, ald_d, N_USER);
    agg_conv1_kernel<<<(N_USER + 3) / 4, 256, 0, stream>>>(
        rowptr_u, csr_u, h_tx, als_s, ald_d, agg, N_USER);
    // u1 = elu(agg @ blockdiag(W1_t2u) + b1) in place; als2 = u1 . vsrc2 fused
    transform_head_kernel<<<dim3((N_USER + 255) / 256, NH), 256, 0, stream>>>(
        agg, W1_t2u, b1_t2u, vsrc2, als2, N_USER, 1);
    float* u1 = agg;

    // ================= conv2, u2t only (h_tx dead; hs2 aliases it) =================
    gemm_kernel<<<dim3(1, (N_USER + 63) / 64), 256, 0, stream>>>(
        u1, W2_u2t, nullptr, hs2, N_USER, HC1, OUTC, 0);
    conv2_fused_kernel<<<(N_TX + 3) / 4, 256, 0, stream>>>(
        rowptr_t, csr_t, hs2, als2, ald2, b2_u2t, Wc, bc, out, N_TX);
}